// Round 4
// baseline (1197.999 us; speedup 1.0000x reference)
//
#include <hip/hip_runtime.h>
#include <hip/hip_fp16.h>
#include <hip/hip_cooperative_groups.h>

namespace cg = cooperative_groups;

#define NN 4096
constexpr int TPB = 256;
constexpr int NSTRIP = 4;                 // column strips of 1024
constexpr int CPB = 1024;
constexpr int RPB = 16;                   // rows per block-tile
constexpr int NROWG = NN / RPB;           // 256 row groups
constexpr int NRSLOT = NSTRIP * (TPB / 64);  // 16 row-partial slots
constexpr int NBLK = NSTRIP * NROWG;      // 1024 blocks

typedef float    f32x4 __attribute__((ext_vector_type(4)));
typedef _Float16 f16x4 __attribute__((ext_vector_type(4)));

__device__ __forceinline__ float sigmoidf_(float x) {
    return 1.0f / (1.0f + __expf(-x));
}

// MODE: 0 = step1 from bf, write fp16 df   1 = step1 from bf, no df
//       2 = mid step from fp16 df          3 = mid step from bf
//       4 = step5 from bf + out_f epilogue
template <int MODE>
__device__ __forceinline__ void pass_phase(
    const float2* __restrict__ bs, const f32x4* __restrict__ bf,
    f16x4* __restrict__ df, f32x4* __restrict__ of,
    const float* __restrict__ s1c, const float* __restrict__ s1p, float w,
    float* __restrict__ rowpart, float* __restrict__ colpart,
    float* __restrict__ s1store) {
    const int t = threadIdx.x;
    const int bid = blockIdx.x;
    const int strip = bid & (NSTRIP - 1);
    const int rg = bid >> 2;
    const int j0 = strip * CPB + t * 4;
    const int i0 = rg * RPB;

    float s0cv[4], ws0p[4];
#pragma unroll
    for (int k = 0; k < 4; ++k) {
        if (MODE <= 1) {
            float2 v = bs[j0 + k];
            s0cv[k] = 1.0f - sigmoidf_(v.y - v.x);
            ws0p[k] = 0.0f;
        } else {
            s0cv[k] = 1.0f - s1c[j0 + k];
            ws0p[k] = w * (1.0f - s1p[j0 + k]);
        }
    }
    if (MODE <= 1) {  // 16 blocks also persist sigma^1 for step 2's prev
        if (bid < NN / TPB) {
            int x = bid * TPB + t;
            float2 v = bs[x];
            s1store[x] = sigmoidf_(v.y - v.x);
        }
    }
    float colacc[4] = {0.f, 0.f, 0.f, 0.f};
    for (int r = 0; r < RPB; ++r) {
        const int i = i0 + r;
        float s1ci, s1pi;
        if (MODE <= 1) {
            float2 v = bs[i];
            s1ci = sigmoidf_(v.y - v.x);
            s1pi = 0.0f;
        } else {
            s1ci = s1c[i];
            s1pi = s1p[i];
        }
        float dd[4];
        if (MODE == 2) {
            f16x4 h = reinterpret_cast<const f16x4*>(df)[((size_t)i * NN + j0) >> 2];
            dd[0] = (float)h.x; dd[1] = (float)h.y;
            dd[2] = (float)h.z; dd[3] = (float)h.w;
        } else {
            const size_t u = ((size_t)i * NN + j0) >> 1;
            f32x4 a = bf[u];
            f32x4 b = bf[u + 1];
            dd[0] = a.y - a.x; dd[1] = a.w - a.z;
            dd[2] = b.y - b.x; dd[3] = b.w - b.z;
            if (MODE == 0) {
                f16x4 h;
                h.x = (_Float16)dd[0]; h.y = (_Float16)dd[1];
                h.z = (_Float16)dd[2]; h.w = (_Float16)dd[3];
                df[((size_t)i * NN + j0) >> 2] = h;
            }
            if (MODE == 4) {
                const float wi = w * s1ci;
                f32x4 oa = {a.x + wi * s0cv[0], a.y, a.z + wi * s0cv[1], a.w};
                f32x4 ob = {b.x + wi * s0cv[2], b.y, b.z + wi * s0cv[3], b.w};
                __builtin_nontemporal_store(oa, of + u);
                __builtin_nontemporal_store(ob, of + u + 1);
            }
        }
        float rowp = 0.f;
#pragma unroll
        for (int k = 0; k < 4; ++k) {
            float f1 = sigmoidf_(dd[k] - s1pi * ws0p[k]);
            colacc[k] += s1ci * f1;
            rowp += f1 * s0cv[k];
        }
#pragma unroll
        for (int off = 32; off > 0; off >>= 1) rowp += __shfl_down(rowp, off);
        if ((t & 63) == 0)
            rowpart[(size_t)(strip * (TPB / 64) + (t >> 6)) * NN + i] = rowp;
    }
    *reinterpret_cast<f32x4*>(colpart + (size_t)rg * NN + j0) =
        f32x4{colacc[0], colacc[1], colacc[2], colacc[3]};
}

// 64 active blocks x 256 thr; wave sl sums its slice of partials, LDS-combine.
__device__ __forceinline__ void update_phase(
    const float* __restrict__ rowpart, const float* __restrict__ colpart,
    const float2* __restrict__ bs, float w,
    float* __restrict__ s1next, float2* __restrict__ out_s, int writeOut) {
    if (blockIdx.x >= NN / 64) return;
    __shared__ float m0s[4][64];
    __shared__ float m1s[4][64];
    const int xl = threadIdx.x & 63;
    const int sl = threadIdx.x >> 6;
    const int x = blockIdx.x * 64 + xl;

    float m1 = 0.f;
    const int g0 = sl * (NROWG / 4);
#pragma unroll 8
    for (int g = g0; g < g0 + NROWG / 4; ++g) m1 += colpart[(size_t)g * NN + x];
    float m0 = 0.f;
    const int s0i = sl * (NRSLOT / 4);
#pragma unroll
    for (int s = s0i; s < s0i + NRSLOT / 4; ++s) m0 += rowpart[(size_t)s * NN + x];
    m0s[sl][xl] = m0;
    m1s[sl][xl] = m1;
    __syncthreads();
    if (sl == 0) {
        m0 = m0s[0][xl] + m0s[1][xl] + m0s[2][xl] + m0s[3][xl];
        m1 = m1s[0][xl] + m1s[1][xl] + m1s[2][xl] + m1s[3][xl];
        float2 b = bs[x];
        float c0 = b.x + w * m0;
        float c1 = b.y + w * m1;
        if (writeOut) out_s[x] = make_float2(c0, c1);
        else s1next[x] = sigmoidf_(c1 - c0);
    }
}

template <int USE_DF>
__global__ __launch_bounds__(TPB, 4) void mega_kernel(
    const float2* __restrict__ bs, const f32x4* __restrict__ bf,
    const float* __restrict__ wptr, float2* __restrict__ out_s,
    f32x4* __restrict__ out_f, float* __restrict__ sa,
    float* __restrict__ sb, float* __restrict__ sc,
    float* __restrict__ rowpart, float* __restrict__ colpart,
    f16x4* __restrict__ df) {
    cg::grid_group grid = cg::this_grid();
    const float w = wptr[0];

    // step 1 (sigma^1 inline, stored to sa)
    pass_phase<USE_DF ? 0 : 1>(bs, bf, df, nullptr, nullptr, nullptr, w,
                               rowpart, colpart, sa);
    grid.sync();
    update_phase(rowpart, colpart, bs, w, sb, nullptr, 0);  // sb = sigma^2
    grid.sync();
    // step 2: cur=sigma^2, prev=sigma^1
    pass_phase<USE_DF ? 2 : 3>(bs, bf, df, nullptr, sb, sa, w, rowpart, colpart, nullptr);
    grid.sync();
    update_phase(rowpart, colpart, bs, w, sc, nullptr, 0);  // sc = sigma^3
    grid.sync();
    // step 3: cur=sigma^3, prev=sigma^2
    pass_phase<USE_DF ? 2 : 3>(bs, bf, df, nullptr, sc, sb, w, rowpart, colpart, nullptr);
    grid.sync();
    update_phase(rowpart, colpart, bs, w, sa, nullptr, 0);  // sa = sigma^4
    grid.sync();
    // step 4: cur=sigma^4, prev=sigma^3
    pass_phase<USE_DF ? 2 : 3>(bs, bf, df, nullptr, sa, sc, w, rowpart, colpart, nullptr);
    grid.sync();
    update_phase(rowpart, colpart, bs, w, sb, nullptr, 0);  // sb = sigma^5
    grid.sync();
    // step 5: cur=sigma^5, prev=sigma^4, fused out_f write
    pass_phase<4>(bs, bf, df, out_f, sb, sa, w, rowpart, colpart, nullptr);
    grid.sync();
    update_phase(rowpart, colpart, bs, w, nullptr, out_s, 1);  // out_s
}

// ---- non-cooperative fallback wrappers ----
template <int MODE>
__global__ __launch_bounds__(TPB) void pass_kernel_g(
    const float2* __restrict__ bs, const f32x4* __restrict__ bf,
    f16x4* __restrict__ df, f32x4* __restrict__ of,
    const float* __restrict__ s1c, const float* __restrict__ s1p,
    const float* __restrict__ wptr,
    float* __restrict__ rowpart, float* __restrict__ colpart,
    float* __restrict__ s1store) {
    pass_phase<MODE>(bs, bf, df, of, s1c, s1p, wptr[0], rowpart, colpart, s1store);
}

__global__ __launch_bounds__(TPB) void update_kernel_g(
    const float* __restrict__ rowpart, const float* __restrict__ colpart,
    const float2* __restrict__ bs, const float* __restrict__ wptr,
    float* __restrict__ s1next, float2* __restrict__ out_s, int writeOut) {
    update_phase(rowpart, colpart, bs, wptr[0], s1next, out_s, writeOut);
}

extern "C" void kernel_launch(void* const* d_in, const int* in_sizes, int n_in,
                              void* d_out, int out_size, void* d_ws,
                              size_t ws_size, hipStream_t stream) {
    const float2* bs = (const float2*)d_in[0];   // (N,2)
    const f32x4* bf = (const f32x4*)d_in[1];     // (N,N,2)
    const float* wptr = (const float*)d_in[2];   // (1,)
    float2* out_s = (float2*)d_out;
    f32x4* out_f = (f32x4*)((float*)d_out + 2 * NN);

    char* ws = (char*)d_ws;
    size_t off = 0;
    auto alloc = [&](size_t bytes) {
        void* p = ws + off;
        off = (off + bytes + 255) & ~(size_t)255;
        return p;
    };
    float* sa = (float*)alloc((size_t)NN * 4);
    float* sb = (float*)alloc((size_t)NN * 4);
    float* sc = (float*)alloc((size_t)NN * 4);
    float* rowpart = (float*)alloc((size_t)NRSLOT * NN * 4);
    float* colpart = (float*)alloc((size_t)NROWG * NN * 4);
    f16x4* df = (f16x4*)(ws + off);
    const bool use_df = (ws_size >= off + (size_t)NN * NN * 2);

    void* args[] = {(void*)&bs, (void*)&bf, (void*)&wptr, (void*)&out_s,
                    (void*)&out_f, (void*)&sa, (void*)&sb, (void*)&sc,
                    (void*)&rowpart, (void*)&colpart, (void*)&df};
    hipError_t err;
    if (use_df) {
        err = hipLaunchCooperativeKernel((const void*)mega_kernel<1>, dim3(NBLK),
                                         dim3(TPB), (void**)args, 0, stream);
    } else {
        err = hipLaunchCooperativeKernel((const void*)mega_kernel<0>, dim3(NBLK),
                                         dim3(TPB), (void**)args, 0, stream);
    }
    if (err == hipSuccess) return;

    // ---- fallback: plain multi-kernel sequence (same math) ----
    if (use_df)
        pass_kernel_g<0><<<NBLK, TPB, 0, stream>>>(bs, bf, df, nullptr, nullptr,
                                                   nullptr, wptr, rowpart, colpart, sa);
    else
        pass_kernel_g<1><<<NBLK, TPB, 0, stream>>>(bs, bf, df, nullptr, nullptr,
                                                   nullptr, wptr, rowpart, colpart, sa);
    update_kernel_g<<<NN / 64, TPB, 0, stream>>>(rowpart, colpart, bs, wptr, sb,
                                                 nullptr, 0);
    if (use_df) {
        pass_kernel_g<2><<<NBLK, TPB, 0, stream>>>(bs, bf, df, nullptr, sb, sa,
                                                   wptr, rowpart, colpart, nullptr);
        update_kernel_g<<<NN / 64, TPB, 0, stream>>>(rowpart, colpart, bs, wptr, sc,
                                                     nullptr, 0);
        pass_kernel_g<2><<<NBLK, TPB, 0, stream>>>(bs, bf, df, nullptr, sc, sb,
                                                   wptr, rowpart, colpart, nullptr);
        update_kernel_g<<<NN / 64, TPB, 0, stream>>>(rowpart, colpart, bs, wptr, sa,
                                                     nullptr, 0);
        pass_kernel_g<2><<<NBLK, TPB, 0, stream>>>(bs, bf, df, nullptr, sa, sc,
                                                   wptr, rowpart, colpart, nullptr);
        update_kernel_g<<<NN / 64, TPB, 0, stream>>>(rowpart, colpart, bs, wptr, sb,
                                                     nullptr, 0);
    } else {
        pass_kernel_g<3><<<NBLK, TPB, 0, stream>>>(bs, bf, df, nullptr, sb, sa,
                                                   wptr, rowpart, colpart, nullptr);
        update_kernel_g<<<NN / 64, TPB, 0, stream>>>(rowpart, colpart, bs, wptr, sc,
                                                     nullptr, 0);
        pass_kernel_g<3><<<NBLK, TPB, 0, stream>>>(bs, bf, df, nullptr, sc, sb,
                                                   wptr, rowpart, colpart, nullptr);
        update_kernel_g<<<NN / 64, TPB, 0, stream>>>(rowpart, colpart, bs, wptr, sa,
                                                     nullptr, 0);
        pass_kernel_g<3><<<NBLK, TPB, 0, stream>>>(bs, bf, df, nullptr, sa, sc,
                                                   wptr, rowpart, colpart, nullptr);
        update_kernel_g<<<NN / 64, TPB, 0, stream>>>(rowpart, colpart, bs, wptr, sb,
                                                     nullptr, 0);
    }
    pass_kernel_g<4><<<NBLK, TPB, 0, stream>>>(bs, bf, df, out_f, sb, sa, wptr,
                                               rowpart, colpart, nullptr);
    update_kernel_g<<<NN / 64, TPB, 0, stream>>>(rowpart, colpart, bs, wptr,
                                                 nullptr, out_s, 1);
}

// Round 5
// 151.470 us; speedup vs baseline: 7.9091x; 7.9091x over previous
//
#include <hip/hip_runtime.h>
#include <hip/hip_fp16.h>

#define NN 4096
constexpr int TPB = 256;
constexpr int NSTRIP = 4;                    // column strips of 1024
constexpr int CPB = 1024;
constexpr int RPB = 16;                      // rows per block-tile
constexpr int NROWG = NN / RPB;              // 256 row groups
constexpr int NRSLOT = NSTRIP * (TPB / 64);  // 16 row-partial slots
constexpr int NBLK = NSTRIP * NROWG;         // 1024 blocks

typedef float    f32x4 __attribute__((ext_vector_type(4)));
typedef _Float16 f16x4 __attribute__((ext_vector_type(4)));

__device__ __forceinline__ float sigmoidf_(float x) {
    return 1.0f / (1.0f + __expf(-x));
}

// MODE: 0 = step1 from bf (sigma^1 inline), write fp16 df
//       1 = step1 from bf, no df write (fallback)
//       2 = mid step from fp16 df          3 = mid step from bf (fallback)
//       4 = step5 from bf + out_f epilogue
template <int MODE>
__global__ __launch_bounds__(TPB) void pass_kernel(
    const float2* __restrict__ bs, const f32x4* __restrict__ bf,
    f16x4* __restrict__ df, f32x4* __restrict__ of,
    const float* __restrict__ s1c, const float* __restrict__ s1p,
    const float* __restrict__ wptr,
    float* __restrict__ rowpart, float* __restrict__ colpart,
    float* __restrict__ s1store) {
    const int t = threadIdx.x;
    const int bid = blockIdx.x;
    const int strip = bid & (NSTRIP - 1);
    const int rg = bid >> 2;
    const int j0 = strip * CPB + t * 4;
    const int i0 = rg * RPB;
    const float w = wptr[0];

    float s0cv[4], ws0p[4];
#pragma unroll
    for (int k = 0; k < 4; ++k) {
        if (MODE <= 1) {
            float2 v = bs[j0 + k];
            s0cv[k] = 1.0f - sigmoidf_(v.y - v.x);
            ws0p[k] = 0.0f;
        } else {
            s0cv[k] = 1.0f - s1c[j0 + k];
            ws0p[k] = w * (1.0f - s1p[j0 + k]);
        }
    }
    if (MODE <= 1) {  // 16 blocks persist sigma^1 for step 2's prev
        if (bid < NN / TPB) {
            int x = bid * TPB + t;
            float2 v = bs[x];
            s1store[x] = sigmoidf_(v.y - v.x);
        }
    }
    float colacc[4] = {0.f, 0.f, 0.f, 0.f};
    for (int r = 0; r < RPB; ++r) {
        const int i = i0 + r;
        float s1ci, s1pi;
        if (MODE <= 1) {
            float2 v = bs[i];
            s1ci = sigmoidf_(v.y - v.x);
            s1pi = 0.0f;
        } else {
            s1ci = s1c[i];
            s1pi = s1p[i];
        }
        float dd[4];
        if (MODE == 2) {
            f16x4 h = reinterpret_cast<const f16x4*>(df)[((size_t)i * NN + j0) >> 2];
            dd[0] = (float)h.x; dd[1] = (float)h.y;
            dd[2] = (float)h.z; dd[3] = (float)h.w;
        } else {
            const size_t u = ((size_t)i * NN + j0) >> 1;
            f32x4 a = bf[u];
            f32x4 b = bf[u + 1];
            dd[0] = a.y - a.x; dd[1] = a.w - a.z;
            dd[2] = b.y - b.x; dd[3] = b.w - b.z;
            if (MODE == 0) {
                f16x4 h;
                h.x = (_Float16)dd[0]; h.y = (_Float16)dd[1];
                h.z = (_Float16)dd[2]; h.w = (_Float16)dd[3];
                df[((size_t)i * NN + j0) >> 2] = h;
            }
            if (MODE == 4) {
                const float wi = w * s1ci;
                f32x4 oa = {a.x + wi * s0cv[0], a.y, a.z + wi * s0cv[1], a.w};
                f32x4 ob = {b.x + wi * s0cv[2], b.y, b.z + wi * s0cv[3], b.w};
                __builtin_nontemporal_store(oa, of + u);
                __builtin_nontemporal_store(ob, of + u + 1);
            }
        }
        float rowp = 0.f;
#pragma unroll
        for (int k = 0; k < 4; ++k) {
            float f1 = sigmoidf_(dd[k] - s1pi * ws0p[k]);
            colacc[k] += s1ci * f1;
            rowp += f1 * s0cv[k];
        }
#pragma unroll
        for (int off = 32; off > 0; off >>= 1) rowp += __shfl_down(rowp, off);
        if ((t & 63) == 0)
            rowpart[(size_t)(strip * (TPB / 64) + (t >> 6)) * NN + i] = rowp;
    }
    *reinterpret_cast<f32x4*>(colpart + (size_t)rg * NN + j0) =
        f32x4{colacc[0], colacc[1], colacc[2], colacc[3]};
}

// 64 blocks x 1024 threads: 16 slices x 64 columns. Slice sl sums colpart
// groups [sl*16, sl*16+16) + rowpart slot sl; LDS combine by slice 0.
__global__ __launch_bounds__(1024) void update_kernel(
    const float* __restrict__ rowpart, const float* __restrict__ colpart,
    const float2* __restrict__ bs, const float* __restrict__ wptr,
    float* __restrict__ s1next, float2* __restrict__ out_s, int writeOut) {
    __shared__ float red0[16][64];
    __shared__ float red1[16][64];
    const int col = threadIdx.x & 63;
    const int sl = threadIdx.x >> 6;  // 0..15
    const int x = blockIdx.x * 64 + col;

    float acc = 0.f;
    const int g0 = sl * (NROWG / 16);
#pragma unroll
    for (int g = g0; g < g0 + NROWG / 16; ++g) acc += colpart[(size_t)g * NN + x];
    red1[sl][col] = acc;
    red0[sl][col] = rowpart[(size_t)sl * NN + x];
    __syncthreads();
    if (sl == 0) {
        float m0 = 0.f, m1 = 0.f;
#pragma unroll
        for (int s = 0; s < 16; ++s) {
            m0 += red0[s][col];
            m1 += red1[s][col];
        }
        float w = wptr[0];
        float2 b = bs[x];
        float c0 = b.x + w * m0;
        float c1 = b.y + w * m1;
        if (writeOut) out_s[x] = make_float2(c0, c1);
        else s1next[x] = sigmoidf_(c1 - c0);
    }
}

extern "C" void kernel_launch(void* const* d_in, const int* in_sizes, int n_in,
                              void* d_out, int out_size, void* d_ws,
                              size_t ws_size, hipStream_t stream) {
    const float2* bs = (const float2*)d_in[0];   // (N,2)
    const f32x4* bf = (const f32x4*)d_in[1];     // (N,N,2)
    const float* wptr = (const float*)d_in[2];   // (1,)
    float2* out_s = (float2*)d_out;
    f32x4* out_f = (f32x4*)((float*)d_out + 2 * NN);

    char* ws = (char*)d_ws;
    size_t off = 0;
    auto alloc = [&](size_t bytes) {
        void* p = ws + off;
        off = (off + bytes + 255) & ~(size_t)255;
        return p;
    };
    float* sa = (float*)alloc((size_t)NN * 4);
    float* sb = (float*)alloc((size_t)NN * 4);
    float* sc = (float*)alloc((size_t)NN * 4);
    float* rowpart = (float*)alloc((size_t)NRSLOT * NN * 4);
    float* colpart = (float*)alloc((size_t)NROWG * NN * 4);
    f16x4* df = (f16x4*)(ws + off);
    const bool use_df = (ws_size >= off + (size_t)NN * NN * 2);

    const dim3 gP(NBLK), bP(TPB);
    const dim3 gU(NN / 64), bU(1024);

    // step 1: sigma^1 inline, df written, sa = sigma^1
    if (use_df)
        pass_kernel<0><<<gP, bP, 0, stream>>>(bs, bf, df, nullptr, nullptr,
                                              nullptr, wptr, rowpart, colpart, sa);
    else
        pass_kernel<1><<<gP, bP, 0, stream>>>(bs, bf, df, nullptr, nullptr,
                                              nullptr, wptr, rowpart, colpart, sa);
    update_kernel<<<gU, bU, 0, stream>>>(rowpart, colpart, bs, wptr, sb, nullptr, 0);  // sb = sigma^2

    if (use_df) {
        // step 2: cur=sigma^2, prev=sigma^1
        pass_kernel<2><<<gP, bP, 0, stream>>>(bs, bf, df, nullptr, sb, sa, wptr,
                                              rowpart, colpart, nullptr);
        update_kernel<<<gU, bU, 0, stream>>>(rowpart, colpart, bs, wptr, sc, nullptr, 0);  // sigma^3
        // step 3
        pass_kernel<2><<<gP, bP, 0, stream>>>(bs, bf, df, nullptr, sc, sb, wptr,
                                              rowpart, colpart, nullptr);
        update_kernel<<<gU, bU, 0, stream>>>(rowpart, colpart, bs, wptr, sa, nullptr, 0);  // sigma^4
        // step 4
        pass_kernel<2><<<gP, bP, 0, stream>>>(bs, bf, df, nullptr, sa, sc, wptr,
                                              rowpart, colpart, nullptr);
        update_kernel<<<gU, bU, 0, stream>>>(rowpart, colpart, bs, wptr, sb, nullptr, 0);  // sigma^5
    } else {
        pass_kernel<3><<<gP, bP, 0, stream>>>(bs, bf, df, nullptr, sb, sa, wptr,
                                              rowpart, colpart, nullptr);
        update_kernel<<<gU, bU, 0, stream>>>(rowpart, colpart, bs, wptr, sc, nullptr, 0);
        pass_kernel<3><<<gP, bP, 0, stream>>>(bs, bf, df, nullptr, sc, sb, wptr,
                                              rowpart, colpart, nullptr);
        update_kernel<<<gU, bU, 0, stream>>>(rowpart, colpart, bs, wptr, sa, nullptr, 0);
        pass_kernel<3><<<gP, bP, 0, stream>>>(bs, bf, df, nullptr, sa, sc, wptr,
                                              rowpart, colpart, nullptr);
        update_kernel<<<gU, bU, 0, stream>>>(rowpart, colpart, bs, wptr, sb, nullptr, 0);
    }
    // step 5: cur=sigma^5 (sb), prev=sigma^4 (sa), fused out_f write
    pass_kernel<4><<<gP, bP, 0, stream>>>(bs, bf, df, out_f, sb, sa, wptr,
                                          rowpart, colpart, nullptr);
    update_kernel<<<gU, bU, 0, stream>>>(rowpart, colpart, bs, wptr, nullptr, out_s, 1);
}